// Round 7
// baseline (963.575 us; speedup 1.0000x reference)
//
#include <hip/hip_runtime.h>
#include <hip/hip_bf16.h>

typedef __attribute__((ext_vector_type(8))) __bf16 bf16x8;
typedef __attribute__((ext_vector_type(8))) _Float16 f16x8;
typedef __attribute__((ext_vector_type(4))) float f32x4;

#define MDIM 16384  // B*T
#define HDIM 2048
#define IDIM 512
#define ODIM 512
#define KCAT 1536   // [s0|s1|s2] concatenated K segments of 512
#define CAP 768     // approx boundary-bin candidate buffer
#define CAPC 64     // exact-fixup candidates per threshold (expect ~1)

static __device__ __forceinline__ unsigned short f2bf(float f) {
  unsigned int u = __float_as_uint(f);
  unsigned int r = (u + 0x7fffu + ((u >> 16) & 1u)) >> 16;
  return (unsigned short)r;
}

// ---------------- f32 -> bf16 (W_dec) ----------------
__global__ void cvt_bf16_kernel(const float* __restrict__ src,
                                unsigned short* __restrict__ dst, int n) {
  int i = (blockIdx.x * 256 + threadIdx.x) * 4;
  if (i >= n) return;
  float4 v = *(const float4*)(src + i);
  unsigned int a = (unsigned int)f2bf(v.x) | ((unsigned int)f2bf(v.y) << 16);
  unsigned int b = (unsigned int)f2bf(v.z) | ((unsigned int)f2bf(v.w) << 16);
  uint2 st; st.x = a; st.y = b;
  *(uint2*)(dst + i) = st;
}

// ---------------- split f32 -> fp16 hi/lo; A layout [hi | lo*2048 | hi] -------
// hi = RNE16(x); lo = RNE16((x-hi)*2048) — residual captured to ~2^-24 of x.
static __device__ __forceinline__ void split_pack(const float4 v, uint2* h2, uint2* l2) {
  float vv[4] = {v.x, v.y, v.z, v.w};
  unsigned int hp[2], lp[2];
#pragma unroll
  for (int j = 0; j < 4; ++j) {
    _Float16 hh = (_Float16)vv[j];
    float back = (float)hh;
    _Float16 ll = (_Float16)((vv[j] - back) * 2048.0f);
    unsigned short hb = __builtin_bit_cast(unsigned short, hh);
    unsigned short lb = __builtin_bit_cast(unsigned short, ll);
    if (j & 1) { hp[j >> 1] |= (unsigned int)hb << 16; lp[j >> 1] |= (unsigned int)lb << 16; }
    else       { hp[j >> 1] = hb; lp[j >> 1] = lb; }
  }
  h2->x = hp[0]; h2->y = hp[1];
  l2->x = lp[0]; l2->y = lp[1];
}

__global__ void split_a_kernel(const float* __restrict__ src,
                               unsigned short* __restrict__ dst) {
  int idx = (blockIdx.x * 256 + threadIdx.x) * 4;
  int row = idx >> 9, col = idx & 511;
  uint2 h2, l2;
  split_pack(*(const float4*)(src + idx), &h2, &l2);
  unsigned short* drow = dst + (size_t)row * KCAT;
  *(uint2*)(drow + col) = h2;          // seg0: hi
  *(uint2*)(drow + 512 + col) = l2;    // seg1: lo*2048
  *(uint2*)(drow + 1024 + col) = h2;   // seg2: hi
}

__global__ void split_b_kernel(const float* __restrict__ src,
                               unsigned short* __restrict__ dst) {
  int idx = (blockIdx.x * 256 + threadIdx.x) * 4;
  int row = idx >> 9, col = idx & 511;
  uint2 h2, l2;
  split_pack(*(const float4*)(src + idx), &h2, &l2);
  unsigned short* drow = dst + (size_t)row * KCAT;
  *(uint2*)(drow + col) = h2;          // seg0: hi   (pairs with A hi  -> hi*hi)
  *(uint2*)(drow + 512 + col) = h2;    // seg1: hi   (pairs with A lo  -> lo*hi)
  *(uint2*)(drow + 1024 + col) = l2;   // seg2: lo   (pairs with A hi  -> hi*lo)
}

// ---------------- GEMM1 (split-fp16 MFMA): h = x@W_enc^T + b_enc to ~2^-24 ----
// h = acc1(seg0) + (acc2(seg1)+acc2(seg2))/2048 + bias. Dropped lo*lo ~ 7e-8.
// 128x128 tile, BK=32, 512 thr / 8 waves; wave = 64x32 (4x2 16x16x32 subtiles).
__global__ __launch_bounds__(512) void gemm1_mfma_kernel(
    const unsigned short* __restrict__ A,   // [M, KCAT] fp16 bits
    const unsigned short* __restrict__ B,   // [HDIM, KCAT] fp16 bits
    const float* __restrict__ benc,         // [HDIM]
    float* __restrict__ h) {                // [M, HDIM] f32
  __shared__ __align__(16) _Float16 As[128 * 32];
  __shared__ __align__(16) _Float16 Bs[128 * 32];
  const int t = threadIdx.x;
  const int lane = t & 63;
  const int w = t >> 6;
  const int wm = w >> 2;       // 0..1  (m half)
  const int wn = w & 3;        // 0..3  (n quarter)
  const int m0 = blockIdx.y * 128;
  const int n0 = blockIdx.x * 128;
  const int r = t >> 2;        // staging row 0..127
  const int k8 = (t & 3) * 8;  // 8-fp16 chunk in BK=32

  f32x4 acc1[4][2], acc2[4][2];
#pragma unroll
  for (int i = 0; i < 4; ++i)
#pragma unroll
    for (int j = 0; j < 2; ++j) {
      acc1[i][j] = (f32x4){0.f, 0.f, 0.f, 0.f};
      acc2[i][j] = (f32x4){0.f, 0.f, 0.f, 0.f};
    }

  const int la = lane & 15;
  const int kq = (lane >> 4) * 8;
  const unsigned short* pa = A + (size_t)(m0 + r) * KCAT + k8;
  const unsigned short* pb = B + (size_t)(n0 + r) * KCAT + k8;

  for (int kt = 0; kt < KCAT; kt += 32) {
    uint4 av = *(const uint4*)(pa + kt);
    uint4 bv = *(const uint4*)(pb + kt);
    __syncthreads();
    *(uint4*)&As[r * 32 + k8] = av;
    *(uint4*)&Bs[r * 32 + k8] = bv;
    __syncthreads();
    f16x8 af[4], bg[2];
#pragma unroll
    for (int mi = 0; mi < 4; ++mi)
      af[mi] = *(const f16x8*)&As[(wm * 64 + mi * 16 + la) * 32 + kq];
#pragma unroll
    for (int ni = 0; ni < 2; ++ni)
      bg[ni] = *(const f16x8*)&Bs[(wn * 32 + ni * 16 + la) * 32 + kq];
    if (kt < 512) {
#pragma unroll
      for (int mi = 0; mi < 4; ++mi)
#pragma unroll
        for (int ni = 0; ni < 2; ++ni)
          acc1[mi][ni] = __builtin_amdgcn_mfma_f32_16x16x32_f16(
              af[mi], bg[ni], acc1[mi][ni], 0, 0, 0);
    } else {
#pragma unroll
      for (int mi = 0; mi < 4; ++mi)
#pragma unroll
        for (int ni = 0; ni < 2; ++ni)
          acc2[mi][ni] = __builtin_amdgcn_mfma_f32_16x16x32_f16(
              af[mi], bg[ni], acc2[mi][ni], 0, 0, 0);
    }
  }
  // C/D: col = lane&15, row = (lane>>4)*4 + reg
  const int rq = (lane >> 4) * 4;
  const float eps = 1.0f / 2048.0f;
#pragma unroll
  for (int mi = 0; mi < 4; ++mi) {
#pragma unroll
    for (int ni = 0; ni < 2; ++ni) {
      int n = n0 + wn * 32 + ni * 16 + la;
      float bd = benc[n];
#pragma unroll
      for (int rr = 0; rr < 4; ++rr) {
        int m = m0 + wm * 64 + mi * 16 + rq + rr;
        h[(size_t)m * HDIM + n] = acc1[mi][ni][rr] + acc2[mi][ni][rr] * eps + bd;
      }
    }
  }
}

// ---------------- selection v5: verified v3 + tiny-window exact fixup ---------
// Approx thresholds from split-fp16 h (error ~3e-7). Channels with
// |h^2 - v| <= 1e-4*sqrt(v) (~160x the h error) get h recomputed with a
// k-SEQUENTIAL f32 fmaf chain (rounding-correlated with np BLAS), exact tau
// found among them, keys patched; verified tail unchanged.
__global__ __launch_bounds__(256) void select_kernel(
    float* __restrict__ hbuf,           // in: approx h [M,HDIM]; out: mask_prev_new
    const int* __restrict__ maskp,      // [M, HDIM]
    const float* __restrict__ x,        // [M, IDIM] f32
    const float* __restrict__ wenc,     // [HDIM, IDIM] f32
    const float* __restrict__ benc,     // [HDIM]
    unsigned short* __restrict__ hs) {  // out: h*mask_share bf16 [M,HDIM]
  const int row = blockIdx.x;
  const int t = threadIdx.x;
  const int lane = t & 63;
  const int w = t >> 6;
  __shared__ int hist[4096];
  __shared__ unsigned int cand512[CAP];
  __shared__ unsigned int cand256[CAP];
  __shared__ float xrow[IDIM];
  __shared__ int cidx[2][CAPC];
  __shared__ float cex[2][CAPC];
  __shared__ int scal[24];
  __shared__ int n512, n256, ncnt0, ncnt1;

  float* hrow = hbuf + (size_t)row * HDIM;
  const int* mrow = maskp + (size_t)row * HDIM;
  float hv[8];
  *(float4*)&hv[0] = *(const float4*)(hrow + t * 8);
  *(float4*)&hv[4] = *(const float4*)(hrow + t * 8 + 4);
  int4 mp0 = *(const int4*)(mrow + t * 8);
  int4 mp1 = *(const int4*)(mrow + t * 8 + 4);
  int mm[8] = {mp0.x, mp0.y, mp0.z, mp0.w, mp1.x, mp1.y, mp1.z, mp1.w};
#pragma unroll
  for (int i = 0; i < 8; ++i) hv[i] = (mm[i] > 0) ? 0.f : hv[i];
  unsigned int key[8];
#pragma unroll
  for (int i = 0; i < 8; ++i) key[i] = __float_as_uint(hv[i] * hv[i]);

  // stage x row for the exact-fixup dots
  *(float2*)&xrow[t * 2] = *(const float2*)(x + (size_t)row * IDIM + t * 2);

#pragma unroll
  for (int i = 0; i < 16; ++i) hist[t + i * 256] = 0;
  if (t == 0) {
    n512 = 0; n256 = 0; ncnt0 = 0; ncnt1 = 0;
    scal[0] = 0; scal[1] = 0x40000000;
    scal[2] = 0; scal[3] = 0x40000000;
  }
  __syncthreads();
#pragma unroll
  for (int i = 0; i < 8; ++i)
    if (key[i]) atomicAdd(&hist[key[i] >> 20], 1);
  __syncthreads();

  if (w == 0) {  // suffix scan over 4096 bins; lane owns [lane*64, +64)
    const int base = lane * 64;
    int s = 0;
#pragma unroll
    for (int i = 0; i < 64; i += 4) {
      int4 hh = *(const int4*)&hist[base + i];
      s += hh.x + hh.y + hh.z + hh.w;
    }
    int rs = s;
#pragma unroll
    for (int d = 1; d < 64; d <<= 1) {
      int o = __shfl_down(rs, d, 64);
      rs += (lane + d < 64) ? o : 0;
    }
    int c = rs - s;
    for (int i = 60; i >= 0; i -= 4) {
      int4 hh = *(const int4*)&hist[base + i];
      int q[4] = {hh.x, hh.y, hh.z, hh.w};
#pragma unroll
      for (int j = 3; j >= 0; --j) {
        int hc = q[j];
        if (c < 512 && c + hc >= 512) { scal[0] = base + i + j; scal[1] = 512 - c; }
        if (c < 256 && c + hc >= 256) { scal[2] = base + i + j; scal[3] = 256 - c; }
        c += hc;
      }
    }
  }
  __syncthreads();
  const int b512 = scal[0], b256 = scal[2];
#pragma unroll
  for (int i = 0; i < 8; ++i) {
    if (key[i]) {
      int bin = (int)(key[i] >> 20);
      if (bin == b512) { int p = atomicAdd(&n512, 1); if (p < CAP) cand512[p] = key[i]; }
      if (bin == b256) { int p = atomicAdd(&n256, 1); if (p < CAP) cand256[p] = key[i]; }
    }
  }
  __syncthreads();

  if (w < 2) {  // approx threshold: wave 0 -> k=512, wave 1 -> k=256
    const unsigned int bb = (unsigned int)scal[w * 2];
    const int r = scal[w * 2 + 1];
    const unsigned int* cand = w ? cand256 : cand512;
    int C = w ? n256 : n512;
    C = (C < CAP) ? C : CAP;
    unsigned int v = 0;
    if (r <= C) {
      v = bb << 20;
      for (int bit = 19; bit >= 0; --bit) {
        unsigned int cth = v | (1u << bit);
        int cnt = 0;
        for (int p = lane; p < C; p += 64) cnt += (cand[p] >= cth) ? 1 : 0;
#pragma unroll
        for (int d = 1; d < 64; d <<= 1) cnt += __shfl_xor(cnt, d, 64);
        if (cnt >= r) v = cth;
      }
    }
    if (lane == 0) scal[4 + w] = (int)v;
  }
  __syncthreads();
  const unsigned int v512a = (unsigned int)scal[4];
  const unsigned int v256a = (unsigned int)scal[5];

  // ---- tiny-window exact fixup ----
  const float vf0 = __uint_as_float(v512a), vf1 = __uint_as_float(v256a);
  const bool act0 = (v512a != 0), act1 = (v256a != 0);
  const float wd0 = 1e-4f * sqrtf(vf0) + 1e-12f;
  const float wd1 = 1e-4f * sqrtf(vf1) + 1e-12f;
  const float hi0 = vf0 + wd0, lo0 = vf0 - wd0;
  const float hi1 = vf1 + wd1, lo1 = vf1 - wd1;
  int gf = 0;  // packed far-above counts
#pragma unroll
  for (int i = 0; i < 8; ++i) {
    float kf = __uint_as_float(key[i]);
    if (act0) {
      if (kf > hi0) gf += 1;
      else if (kf >= lo0) { int p = atomicAdd(&ncnt0, 1); if (p < CAPC) cidx[0][p] = t * 8 + i; }
    }
    if (act1) {
      if (kf > hi1) gf += (1 << 16);
      else if (kf >= lo1) { int p = atomicAdd(&ncnt1, 1); if (p < CAPC) cidx[1][p] = t * 8 + i; }
    }
  }
#pragma unroll
  for (int d = 1; d < 64; d <<= 1) gf += __shfl_xor(gf, d, 64);
  if (lane == 0) scal[16 + w] = gf;
  __syncthreads();
  const int gft = scal[16] + scal[17] + scal[18] + scal[19];
  const int t0n = (ncnt0 < CAPC) ? ncnt0 : CAPC;
  const int t1n = (ncnt1 < CAPC) ? ncnt1 : CAPC;

  // exact dots: k-SEQUENTIAL left-fold fmaf per lane (np-BLAS-correlated order)
  if (w < 2) {
    const int n = w ? t1n : t0n;
    if (lane < n) {
      const int ch = cidx[w][lane];
      const float* wr = wenc + (size_t)ch * IDIM;
      float s = 0.f;
      for (int k = 0; k < IDIM; ++k) s = fmaf(xrow[k], wr[k], s);
      cex[w][lane] = s + benc[ch];
    }
  }
  __syncthreads();

  if (w < 2) {  // exact tau among candidates; overrides approx v
    const bool act = w ? act1 : act0;
    const int n = w ? t1n : t0n;
    if (act && n > 0) {
      int rr = (w ? 256 : 512) - (w ? (gft >> 16) : (gft & 0xffff));
      rr = (rr < 1) ? 1 : ((rr > n) ? n : rr);
      unsigned int v = 0;
      for (int b = 31; b >= 0; --b) {
        unsigned int cth = v | (1u << b);
        int cnt = 0;
        for (int j = lane; j < n; j += 64) {
          float q = cex[w][j];
          cnt += (__float_as_uint(q * q) >= cth) ? 1 : 0;
        }
#pragma unroll
        for (int d = 1; d < 64; d <<= 1) cnt += __shfl_xor(cnt, d, 64);
        if (cnt >= rr) v = cth;
      }
      if (lane == 0) scal[4 + w] = (int)v;
    }
  }
  __syncthreads();
  const unsigned int v512 = (unsigned int)scal[4];
  const unsigned int v256 = (unsigned int)scal[5];

  // patch candidate channels with exact values (by channel ownership)
  for (int j = 0; j < t0n; ++j) {
    int ch = cidx[0][j];
    if ((ch >> 3) == t) { float e = cex[0][j]; hv[ch & 7] = e; key[ch & 7] = __float_as_uint(e * e); }
  }
  for (int j = 0; j < t1n; ++j) {
    int ch = cidx[1][j];
    if ((ch >> 3) == t) { float e = cex[1][j]; hv[ch & 7] = e; key[ch & 7] = __float_as_uint(e * e); }
  }

  // ---- verified tail (unchanged) ----
  int g = 0;
#pragma unroll
  for (int i = 0; i < 8; ++i) {
    g += (key[i] > v512) ? 1 : 0;
    g += (key[i] > v256) ? (1 << 16) : 0;
  }
#pragma unroll
  for (int d = 1; d < 64; d <<= 1) g += __shfl_xor(g, d, 64);
  if (lane == 0) scal[8 + w] = g;
  __syncthreads();
  g = scal[8] + scal[9] + scal[10] + scal[11];
  const int r512 = 512 - (g & 0xffff);
  const int r256 = 256 - (g >> 16);

  int tc = 0;
#pragma unroll
  for (int i = 0; i < 8; ++i) {
    tc += (key[i] == v512) ? 1 : 0;
    tc += (key[i] == v256) ? (1 << 16) : 0;
  }
  int sc = tc;
#pragma unroll
  for (int d = 1; d < 64; d <<= 1) {
    int o = __shfl_up(sc, d, 64);
    if (lane >= d) sc += o;
  }
  if (lane == 63) scal[12 + w] = sc;
  __syncthreads();
  int excl = sc - tc;
  for (int i = 0; i < w; ++i) excl += scal[12 + i];
  int run512 = excl & 0xffff;
  int run256 = (excl >> 16) & 0xffff;

  float mpn[8];
  unsigned int hb[4];
#pragma unroll
  for (int i = 0; i < 8; ++i) {
    bool share, cur;
    if (key[i] > v512) share = true;
    else if (key[i] == v512) { share = (run512 < r512); run512++; }
    else share = false;
    if (key[i] > v256) cur = true;
    else if (key[i] == v256) { cur = (run256 < r256); run256++; }
    else cur = false;
    mpn[i] = (float)mm[i] + (cur ? 1.0f : 0.0f);
    unsigned short bbits = f2bf(share ? hv[i] : 0.0f);
    if (i & 1) hb[i >> 1] |= ((unsigned int)bbits << 16);
    else hb[i >> 1] = (unsigned int)bbits;
  }
  float4 s0 = {mpn[0], mpn[1], mpn[2], mpn[3]};
  float4 s1 = {mpn[4], mpn[5], mpn[6], mpn[7]};
  *(float4*)(hrow + t * 8) = s0;
  *(float4*)(hrow + t * 8 + 4) = s1;
  uint4 hstore = {hb[0], hb[1], hb[2], hb[3]};
  *(uint4*)(hs + (size_t)row * HDIM + t * 8) = hstore;
}

// ---------------- GEMM2: out = hs @ W_dec^T + b_dec (bf16 MFMA, round-4) ------
__global__ __launch_bounds__(256) void gemm2_kernel(
    const unsigned short* __restrict__ A,  // hs bf16 [M, HDIM]
    const unsigned short* __restrict__ B,  // W_dec bf16 [ODIM, HDIM]
    const float* __restrict__ bdec,        // [ODIM]
    float* __restrict__ out) {             // [M, ODIM] f32
  __shared__ __align__(16) __bf16 As[64 * 32];
  __shared__ __align__(16) __bf16 Bs[128 * 32];
  const int t = threadIdx.x;
  const int lane = t & 63;
  const int w = t >> 6;
  const int wm = w >> 1, wn = w & 1;
  const int m0 = blockIdx.y * 64;
  const int n0 = blockIdx.x * 128;
  const int r = t >> 2;
  const int k8 = (t & 3) * 8;

  f32x4 acc[2][4];
#pragma unroll
  for (int i = 0; i < 2; ++i)
#pragma unroll
    for (int j = 0; j < 4; ++j) acc[i][j] = (f32x4){0.f, 0.f, 0.f, 0.f};

  const int la = lane & 15;
  const int kq = (lane >> 4) * 8;

  for (int kt = 0; kt < HDIM; kt += 32) {
    uint4 a0 = *(const uint4*)(A + (size_t)(m0 + r) * HDIM + kt + k8);
    uint4 b0 = *(const uint4*)(B + (size_t)(n0 + r) * HDIM + kt + k8);
    uint4 b1 = *(const uint4*)(B + (size_t)(n0 + 64 + r) * HDIM + kt + k8);
    __syncthreads();
    *(uint4*)&As[r * 32 + k8] = a0;
    *(uint4*)&Bs[r * 32 + k8] = b0;
    *(uint4*)&Bs[(64 + r) * 32 + k8] = b1;
    __syncthreads();
    bf16x8 af[2], bg[4];
#pragma unroll
    for (int mi = 0; mi < 2; ++mi)
      af[mi] = *(const bf16x8*)&As[(wm * 32 + mi * 16 + la) * 32 + kq];
#pragma unroll
    for (int ni = 0; ni < 4; ++ni)
      bg[ni] = *(const bf16x8*)&Bs[(wn * 64 + ni * 16 + la) * 32 + kq];
#pragma unroll
    for (int mi = 0; mi < 2; ++mi)
#pragma unroll
      for (int ni = 0; ni < 4; ++ni)
        acc[mi][ni] = __builtin_amdgcn_mfma_f32_16x16x32_bf16(
            af[mi], bg[ni], acc[mi][ni], 0, 0, 0);
  }
  const int rq = (lane >> 4) * 4;
#pragma unroll
  for (int mi = 0; mi < 2; ++mi) {
#pragma unroll
    for (int ni = 0; ni < 4; ++ni) {
      int n = n0 + wn * 64 + ni * 16 + la;
      float bd = bdec[n];
#pragma unroll
      for (int rr = 0; rr < 4; ++rr) {
        int m = m0 + wm * 32 + mi * 16 + rq + rr;
        out[(size_t)m * ODIM + n] = acc[mi][ni][rr] + bd;
      }
    }
  }
}

extern "C" void kernel_launch(void* const* d_in, const int* in_sizes, int n_in,
                              void* d_out, int out_size, void* d_ws, size_t ws_size,
                              hipStream_t stream) {
  const float* x = (const float*)d_in[0];
  const int* mask_prev = (const int*)d_in[1];
  const float* W_enc = (const float*)d_in[2];
  const float* b_enc = (const float*)d_in[3];
  const float* W_dec = (const float*)d_in[4];
  const float* b_dec = (const float*)d_in[5];

  float* out = (float*)d_out;                       // [M, ODIM] (written by gemm2 last)
  float* hbuf = out + (size_t)MDIM * ODIM;          // h / mask_prev_new slot
  // ws layout: acat [M,1536] fp16 (48 MB) lives where hs (67 MB) later goes —
  // acat is dead once gemm1 completes (stream-ordered). wdec at +67 MB.
  unsigned short* acat = (unsigned short*)d_ws;
  unsigned short* hs = (unsigned short*)d_ws;
  unsigned short* wdec = hs + (size_t)MDIM * HDIM;
  // bcat [HDIM,1536] fp16 (6 MB) in the out region (dead before gemm2 writes).
  unsigned short* bcat = (unsigned short*)d_out;

  split_a_kernel<<<dim3((MDIM * IDIM) / 1024), dim3(256), 0, stream>>>(x, acat);
  split_b_kernel<<<dim3((HDIM * IDIM) / 1024), dim3(256), 0, stream>>>(W_enc, bcat);
  cvt_bf16_kernel<<<dim3((ODIM * HDIM) / 1024), dim3(256), 0, stream>>>(
      W_dec, wdec, ODIM * HDIM);
  gemm1_mfma_kernel<<<dim3(HDIM / 128, MDIM / 128), dim3(512), 0, stream>>>(
      acat, bcat, b_enc, hbuf);
  select_kernel<<<dim3(MDIM), dim3(256), 0, stream>>>(
      hbuf, mask_prev, x, W_enc, b_enc, hs);
  gemm2_kernel<<<dim3(ODIM / 128, MDIM / 64), dim3(256), 0, stream>>>(
      hs, wdec, b_dec, out);
}